// Round 1
// baseline (493.427 us; speedup 1.0000x reference)
//
#include <hip/hip_runtime.h>
#include <math.h>

typedef unsigned short ushort_t;
typedef __attribute__((ext_vector_type(4))) float f32x4;
typedef __attribute__((ext_vector_type(8))) __bf16 bf16x8;
typedef __attribute__((ext_vector_type(8))) unsigned short u16x8;
typedef __attribute__((ext_vector_type(4))) unsigned short u16x4;

#define DEV __device__ __forceinline__

// ---------- constants ----------
// B=4, L=2048, D=1024, H=16, HD=64, M=B*L=8192
#define CB 4
#define CL 2048
#define CD 1024
#define CH 16
#define CHD 64
#define CM 8192

DEV float bf2f(ushort_t u) {
  unsigned int x = ((unsigned int)u) << 16;
  return __builtin_bit_cast(float, x);
}
DEV ushort_t f2bf(float f) {
  unsigned int u = __builtin_bit_cast(unsigned int, f);
  u += 0x7FFFu + ((u >> 16) & 1u);
  return (ushort_t)(u >> 16);
}
DEV void gload16(const void* g, void* l) {
  __builtin_amdgcn_global_load_lds((const __attribute__((address_space(1))) void*)g,
                                   (__attribute__((address_space(3))) void*)l, 16, 0, 0);
}
// read one 16B MFMA fragment from a [rows][64] ushort LDS tile with XOR(row&7) slot swizzle
DEV bf16x8 frag64(const ushort_t* s, int row, int slog) {
  int sl = slog ^ (row & 7);
  return __builtin_bit_cast(bf16x8, *reinterpret_cast<const u16x8*>(s + row * 64 + sl * 8));
}

// ---------- rope tables (bf16) ----------
__global__ void k_rope_tables(ushort_t* __restrict__ cosT, ushort_t* __restrict__ sinT) {
  int idx = blockIdx.x * 256 + threadIdx.x;  // L*512 = 1048576
  int l = idx >> 9, j = idx & 511;
  float theta = powf(10000.0f, -(float)j * (1.0f / 512.0f));
  float ang = (float)l * theta;
  float s, c;
  sincosf(ang, &s, &c);
  cosT[idx] = f2bf(c);
  sinT[idx] = f2bf(s);
}

// ---------- transpose + fp32->bf16: src[R][C] -> dst[C][R] ----------
__global__ void k_transpose_bf16(const float* __restrict__ src, ushort_t* __restrict__ dst,
                                 int R, int C) {
  __shared__ float tile[32][33];
  int c0 = blockIdx.x * 32, r0 = blockIdx.y * 32;
  int tx = threadIdx.x & 31, ty = threadIdx.x >> 5;  // 32 x 8
#pragma unroll
  for (int i = 0; i < 32; i += 8) tile[ty + i][tx] = src[(size_t)(r0 + ty + i) * C + c0 + tx];
  __syncthreads();
#pragma unroll
  for (int i = 0; i < 32; i += 8) dst[(size_t)(c0 + ty + i) * R + r0 + tx] = f2bf(tile[tx][ty + i]);
}

// ---------- layernorm: fp32 in -> bf16 out (one block per row of 1024) ----------
__global__ __launch_bounds__(256) void k_layernorm(const float* __restrict__ x,
                                                   const float* __restrict__ g,
                                                   const float* __restrict__ b,
                                                   ushort_t* __restrict__ out) {
  int row = blockIdx.x, t = threadIdx.x;
  const float* xr = x + (size_t)row * CD;
  f32x4 v = ((const f32x4*)xr)[t];
  float s = v.x + v.y + v.z + v.w;
  float s2 = v.x * v.x + v.y * v.y + v.z * v.z + v.w * v.w;
#pragma unroll
  for (int off = 32; off >= 1; off >>= 1) {
    s += __shfl_xor(s, off);
    s2 += __shfl_xor(s2, off);
  }
  __shared__ float red[8];
  int lane = t & 63, w = t >> 6;
  if (lane == 0) { red[w] = s; red[w + 4] = s2; }
  __syncthreads();
  s = red[0] + red[1] + red[2] + red[3];
  s2 = red[4] + red[5] + red[6] + red[7];
  float mu = s * (1.0f / CD);
  float var = s2 * (1.0f / CD) - mu * mu;
  float rs = rsqrtf(var + 1e-12f);
  f32x4 gg = ((const f32x4*)g)[t];
  f32x4 bb = ((const f32x4*)b)[t];
  u16x4 o;
  o.x = f2bf((v.x - mu) * rs * gg.x + bb.x);
  o.y = f2bf((v.y - mu) * rs * gg.y + bb.y);
  o.z = f2bf((v.z - mu) * rs * gg.z + bb.z);
  o.w = f2bf((v.w - mu) * rs * gg.w + bb.w);
  ((u16x4*)(out + (size_t)row * CD))[t] = o;
}

// ---------- bf16 GEMM: C[M x N] = A[M x K] * Bt[N x K]^T, fused epilogues ----------
enum { EP_PLAIN = 0, EP_SILU = 1, EP_ELU1 = 2, EP_GELU = 3, EP_ADDX = 4 };

template <int EP>
__global__ __launch_bounds__(256, 2) void k_gemm(const ushort_t* __restrict__ A,
                                                 const ushort_t* __restrict__ Bt, int N, int K,
                                                 const float* __restrict__ bias,
                                                 const float* __restrict__ addf,
                                                 float* __restrict__ outf,
                                                 ushort_t* __restrict__ outb) {
  __shared__ __align__(16) ushort_t sA[128 * 64];
  __shared__ __align__(16) ushort_t sB[128 * 64];
  const int t = threadIdx.x;
  const int lane = t & 63;
  const int w = t >> 6;
  const int wr = w >> 1, wc = w & 1;
  const int m0 = blockIdx.y * 128, n0 = blockIdx.x * 128;

  f32x4 acc[4][4];
#pragma unroll
  for (int i = 0; i < 4; ++i)
#pragma unroll
    for (int j = 0; j < 4; ++j) acc[i][j] = f32x4{0.f, 0.f, 0.f, 0.f};

  for (int kt = 0; kt < K; kt += 64) {
#pragma unroll
    for (int i = 0; i < 4; ++i) {
      int c = t + i * 256;       // 1024 chunks of 16B per 128x64 tile
      int row = c >> 3;          // 8 chunks per 64-elem row
      int sl = (c & 7) ^ (row & 7);  // pre-swizzled global source, linear LDS dest
      int ldsoff = (w * 64 + i * 256) * 8;  // wave-uniform base (ushort units)
      gload16(A + (size_t)(m0 + row) * K + kt + sl * 8, sA + ldsoff);
      gload16(Bt + (size_t)(n0 + row) * K + kt + sl * 8, sB + ldsoff);
    }
    __syncthreads();
#pragma unroll
    for (int kk = 0; kk < 2; ++kk) {
      int slog = kk * 4 + (lane >> 4);
      bf16x8 af[4], bfr[4];
#pragma unroll
      for (int mi = 0; mi < 4; ++mi) af[mi] = frag64(sA, wr * 64 + mi * 16 + (lane & 15), slog);
#pragma unroll
      for (int ni = 0; ni < 4; ++ni) bfr[ni] = frag64(sB, wc * 64 + ni * 16 + (lane & 15), slog);
#pragma unroll
      for (int mi = 0; mi < 4; ++mi)
#pragma unroll
        for (int ni = 0; ni < 4; ++ni)
          acc[mi][ni] =
              __builtin_amdgcn_mfma_f32_16x16x32_bf16(af[mi], bfr[ni], acc[mi][ni], 0, 0, 0);
    }
    __syncthreads();
  }

#pragma unroll
  for (int mi = 0; mi < 4; ++mi) {
#pragma unroll
    for (int ni = 0; ni < 4; ++ni) {
      int col = n0 + wc * 64 + ni * 16 + (lane & 15);
      float bc = bias[col];
#pragma unroll
      for (int r = 0; r < 4; ++r) {
        int row = m0 + wr * 64 + mi * 16 + (lane >> 4) * 4 + r;
        size_t idx = (size_t)row * N + col;
        float vv = acc[mi][ni][r] + bc;
        if constexpr (EP == EP_PLAIN) {
          outb[idx] = f2bf(vv);
        } else if constexpr (EP == EP_SILU) {
          outb[idx] = f2bf(vv / (1.f + expf(-vv)));
        } else if constexpr (EP == EP_ELU1) {
          outb[idx] = f2bf(vv > 0.f ? vv + 1.f : expf(vv));
        } else if constexpr (EP == EP_GELU) {
          outb[idx] = f2bf(0.5f * vv * (1.f + erff(vv * 0.70710678118654752f)));
        } else {  // EP_ADDX: fp32 out = addf + gemm + bias
          outf[idx] = addf[idx] + vv;
        }
      }
    }
  }
}

// ---------- attention reduce: per (b,h,lsplit): kv[e][d]=sum_l v[l,e]*k_rope[l,d]; kmean ----------
__global__ __launch_bounds__(256) void k_attn_reduce(const ushort_t* __restrict__ qk,
                                                     const ushort_t* __restrict__ vbf,
                                                     const ushort_t* __restrict__ cosT,
                                                     const ushort_t* __restrict__ sinT,
                                                     float* __restrict__ kvpart,
                                                     float* __restrict__ kmpart) {
  int bh = blockIdx.x >> 2, ls = blockIdx.x & 3;
  int b = bh >> 4, h = bh & 15;
  int t = threadIdx.x, lane = t & 63, w = t >> 6;

  __shared__ float kst[64][68];
  __shared__ __align__(16) ushort_t krT[64 * 64];  // [d][l] swizzled
  __shared__ __align__(16) ushort_t vT[64 * 64];   // [e][l] swizzled
  __shared__ float cst[64][32];
  __shared__ float snt[64][32];
  __shared__ float kmp[4][64];

  float kmacc = 0.f;
  f32x4 acc[4];
#pragma unroll
  for (int i = 0; i < 4; ++i) acc[i] = f32x4{0.f, 0.f, 0.f, 0.f};

  for (int c = ls * 8; c < ls * 8 + 8; ++c) {
    int l0 = c * 64;
    for (int idx = t; idx < 4096; idx += 256) {
      int l = idx >> 6, d = idx & 63;  // d fixed == t&63 across iterations
      size_t grow = (size_t)(b * CL + l0 + l);
      float kvv = bf2f(qk[grow * 2048 + 1024 + h * 64 + d]);
      kst[l][d] = kvv;
      kmacc += kvv;
      ushort_t vv = vbf[grow * CD + h * 64 + d];
      int sl = (l >> 3) ^ (d & 7);
      vT[d * 64 + sl * 8 + (l & 7)] = vv;
    }
    for (int idx = t; idx < 2048; idx += 256) {
      int l = idx >> 5, j = idx & 31;
      size_t p = (size_t)(l0 + l) * 512 + h * 32 + j;
      cst[l][j] = bf2f(cosT[p]);
      snt[l][j] = bf2f(sinT[p]);
    }
    __syncthreads();
    for (int idx = t; idx < 4096; idx += 256) {
      int l = idx >> 6, d = idx & 63, j = d >> 1;
      float cc = cst[l][j], sn = snt[l][j];
      float kr = (d & 1) ? (kst[l][d - 1] * sn + kst[l][d] * cc)
                         : (kst[l][d] * cc - kst[l][d + 1] * sn);
      int sl = (l >> 3) ^ (d & 7);
      krT[d * 64 + sl * 8 + (l & 7)] = f2bf(kr);
    }
    __syncthreads();
#pragma unroll
    for (int kk = 0; kk < 2; ++kk) {
      int slog = kk * 4 + (lane >> 4);
      bf16x8 a = frag64(vT, w * 16 + (lane & 15), slog);  // rows = e
#pragma unroll
      for (int ni = 0; ni < 4; ++ni) {
        bf16x8 bb = frag64(krT, ni * 16 + (lane & 15), slog);  // cols = d
        acc[ni] = __builtin_amdgcn_mfma_f32_16x16x32_bf16(a, bb, acc[ni], 0, 0, 0);
      }
    }
    __syncthreads();
  }
  float* kp = kvpart + ((size_t)(bh * 4 + ls)) * 4096;
#pragma unroll
  for (int ni = 0; ni < 4; ++ni) {
    int d = ni * 16 + (lane & 15);
#pragma unroll
    for (int r = 0; r < 4; ++r) {
      int e = w * 16 + (lane >> 4) * 4 + r;
      kp[e * 64 + d] = acc[ni][r];
    }
  }
  kmp[t >> 6][t & 63] = kmacc;
  __syncthreads();
  if (t < 64) kmpart[(bh * 4 + ls) * 64 + t] = kmp[0][t] + kmp[1][t] + kmp[2][t] + kmp[3][t];
}

// ---------- reduce partials: kvT bf16 [bh][e][d], kmean fp32 [bh][d] ----------
__global__ void k_kv_reduce(const float* __restrict__ kvpart, const float* __restrict__ kmpart,
                            ushort_t* __restrict__ kvT, float* __restrict__ kmean) {
  int gid = blockIdx.x * 256 + threadIdx.x;  // 64*4096
  int bh = gid >> 12, r = gid & 4095;
  float s = 0.f;
#pragma unroll
  for (int ls = 0; ls < 4; ++ls) s += kvpart[((size_t)(bh * 4 + ls)) * 4096 + r];
  kvT[gid] = f2bf(s);
  if (gid < 64 * 64) {
    int bh2 = gid >> 6, d = gid & 63;
    float m = 0.f;
#pragma unroll
    for (int ls = 0; ls < 4; ++ls) m += kmpart[(bh2 * 4 + ls) * 64 + d];
    kmean[gid] = m;
  }
}

// ---------- attention out: out[l][e] = z[l]/L * sum_d q_rope[l][d]*kv[d][e] ----------
__global__ __launch_bounds__(256) void k_attn_out(const ushort_t* __restrict__ qk,
                                                  const ushort_t* __restrict__ kvT,
                                                  const float* __restrict__ kmean,
                                                  const ushort_t* __restrict__ cosT,
                                                  const ushort_t* __restrict__ sinT,
                                                  float* __restrict__ outlin) {
  int bid = blockIdx.x;  // bh*32 + lt
  int bh = bid >> 5, lt = bid & 31;
  int b = bh >> 4, h = bh & 15;
  int l0 = lt * 64;
  int t = threadIdx.x, lane = t & 63, w = t >> 6;

  __shared__ float qst[64][68];
  __shared__ __align__(16) ushort_t qrT[64 * 64];  // [l][d] swizzled
  __shared__ __align__(16) ushort_t kvs[64 * 64];  // [e][d] swizzled
  __shared__ float cst[64][32];
  __shared__ float snt[64][32];
  __shared__ float kms[64];
  __shared__ float zrow[64];

  if (t < 64) kms[t] = kmean[bh * 64 + t];
  for (int idx = t; idx < 4096; idx += 256) {
    int l = idx >> 6, d = idx & 63;
    qst[l][d] = bf2f(qk[(size_t)(b * CL + l0 + l) * 2048 + h * 64 + d]);
    ushort_t kvv = kvT[(size_t)bh * 4096 + idx];
    int e = idx >> 6, dd = idx & 63;
    int sl = (dd >> 3) ^ (e & 7);
    kvs[e * 64 + sl * 8 + (dd & 7)] = kvv;
  }
  for (int idx = t; idx < 2048; idx += 256) {
    int l = idx >> 5, j = idx & 31;
    size_t p = (size_t)(l0 + l) * 512 + h * 32 + j;
    cst[l][j] = bf2f(cosT[p]);
    snt[l][j] = bf2f(sinT[p]);
  }
  __syncthreads();
  for (int idx = t; idx < 4096; idx += 256) {
    int l = idx >> 6, d = idx & 63, j = d >> 1;
    float cc = cst[l][j], sn = snt[l][j];
    float qr = (d & 1) ? (qst[l][d - 1] * sn + qst[l][d] * cc)
                       : (qst[l][d] * cc - qst[l][d + 1] * sn);
    int sl = (d >> 3) ^ (l & 7);
    qrT[l * 64 + sl * 8 + (d & 7)] = f2bf(qr);
  }
  if (t < 64) {
    float dot = 0.f;
#pragma unroll
    for (int d = 0; d < 64; ++d) dot += qst[t][d] * kms[d];
    zrow[t] = 1.0f / (dot * (1.0f / (float)CL) + 1e-6f);
  }
  __syncthreads();
  f32x4 acc[4];
#pragma unroll
  for (int i = 0; i < 4; ++i) acc[i] = f32x4{0.f, 0.f, 0.f, 0.f};
#pragma unroll
  for (int kk = 0; kk < 2; ++kk) {
    int slog = kk * 4 + (lane >> 4);
    bf16x8 a = frag64(qrT, w * 16 + (lane & 15), slog);
#pragma unroll
    for (int ni = 0; ni < 4; ++ni) {
      bf16x8 bb = frag64(kvs, ni * 16 + (lane & 15), slog);
      acc[ni] = __builtin_amdgcn_mfma_f32_16x16x32_bf16(a, bb, acc[ni], 0, 0, 0);
    }
  }
#pragma unroll
  for (int ni = 0; ni < 4; ++ni) {
    int e = ni * 16 + (lane & 15);
#pragma unroll
    for (int r = 0; r < 4; ++r) {
      int l = w * 16 + (lane >> 4) * 4 + r;
      float val = acc[ni][r] * zrow[l] * (1.0f / (float)CL);
      outlin[(size_t)(b * CL + l0 + l) * CD + h * 64 + e] = val;
    }
  }
}

// ---------- conv (depthwise causal k=4) + silu + add attn + mul act_res -> bf16 ----------
__global__ void k_conv_mul(const float* __restrict__ outlin, const ushort_t* __restrict__ vbf,
                           const ushort_t* __restrict__ act, const float* __restrict__ convw,
                           const float* __restrict__ convb, ushort_t* __restrict__ A4) {
  int idx = blockIdx.x * 256 + threadIdx.x;  // B*L*D
  int d = idx & 1023;
  int bl = idx >> 10;
  int l = bl & 2047;
  float accv = 0.f;
#pragma unroll
  for (int tt = 0; tt < 4; ++tt) {
    int ll = l - 3 + tt;
    if (ll >= 0) accv += bf2f(vbf[(size_t)(bl - 3 + tt) * CD + d]) * convw[d * 4 + tt];
  }
  accv += convb[d];
  accv = accv / (1.f + expf(-accv));  // silu
  float a4 = (outlin[idx] + accv) * bf2f(act[idx]);
  A4[idx] = f2bf(a4);
}

// ---------- launch ----------
extern "C" void kernel_launch(void* const* d_in, const int* in_sizes, int n_in, void* d_out,
                              int out_size, void* d_ws, size_t ws_size, hipStream_t stream) {
  const float* x = (const float*)d_in[0];
  const float* ln1_g = (const float*)d_in[1];
  const float* ln1_b = (const float*)d_in[2];
  const float* ln2_g = (const float*)d_in[3];
  const float* ln2_b = (const float*)d_in[4];
  const float* W_act = (const float*)d_in[5];
  const float* b_act = (const float*)d_in[6];
  const float* W_in = (const float*)d_in[7];
  const float* b_in = (const float*)d_in[8];
  const float* W_qk = (const float*)d_in[9];
  const float* b_qk = (const float*)d_in[10];
  const float* conv_w = (const float*)d_in[11];
  const float* conv_b = (const float*)d_in[12];
  const float* W_out = (const float*)d_in[13];
  const float* b_out = (const float*)d_in[14];
  const float* W1 = (const float*)d_in[15];
  const float* b1 = (const float*)d_in[16];
  const float* W2 = (const float*)d_in[17];
  const float* b2 = (const float*)d_in[18];
  float* out = (float*)d_out;

  char* w = (char*)d_ws;
  size_t off = 0;
  auto alloc = [&](size_t bytes) {
    void* p = (void*)(w + off);
    off += (bytes + 255) & ~(size_t)255;
    return p;
  };
  const size_t MB = 1024 * 1024;
  ushort_t* cosT = (ushort_t*)alloc((size_t)CL * 512 * 2);
  ushort_t* sinT = (ushort_t*)alloc((size_t)CL * 512 * 2);
  ushort_t* WactT = (ushort_t*)alloc((size_t)1024 * 1024 * 2);
  ushort_t* WinT = (ushort_t*)alloc((size_t)1024 * 1024 * 2);
  ushort_t* WqkT = (ushort_t*)alloc((size_t)2048 * 1024 * 2);
  ushort_t* WoutT = (ushort_t*)alloc((size_t)1024 * 1024 * 2);
  ushort_t* W1T = (ushort_t*)alloc((size_t)4096 * 1024 * 2);
  ushort_t* W2T = (ushort_t*)alloc((size_t)1024 * 4096 * 2);
  ushort_t* kvTb = (ushort_t*)alloc((size_t)64 * 4096 * 2);
  float* kmean = (float*)alloc((size_t)64 * 64 * 4);
  float* kvpart = (float*)alloc((size_t)256 * 4096 * 4);
  float* kmpart = (float*)alloc((size_t)256 * 64 * 4);
  float* x2 = (float*)alloc((size_t)CM * CD * 4);
  // region R1 (64MB head aliased by G): hln(16) qk(32) act(16), then v separate
  char* R1 = (char*)alloc(64 * MB);
  ushort_t* hln = (ushort_t*)R1;
  ushort_t* qkb = (ushort_t*)(R1 + 16 * MB);
  ushort_t* actb = (ushort_t*)(R1 + 48 * MB);
  ushort_t* Gb = (ushort_t*)R1;  // 64MB alias (hln/qk/act all dead before GEMM5)
  ushort_t* vb = (ushort_t*)alloc(16 * MB);
  // region R2: outlin(32) A4(16); mln aliases outlin (dead after conv_mul)
  char* R2 = (char*)alloc(48 * MB);
  float* outlin = (float*)R2;
  ushort_t* A4 = (ushort_t*)(R2 + 32 * MB);
  ushort_t* mln = (ushort_t*)R2;

  (void)in_sizes; (void)n_in; (void)out_size; (void)ws_size;

  k_rope_tables<<<4096, 256, 0, stream>>>(cosT, sinT);
  k_transpose_bf16<<<dim3(32, 32), 256, 0, stream>>>(W_act, WactT, 1024, 1024);
  k_transpose_bf16<<<dim3(32, 32), 256, 0, stream>>>(W_in, WinT, 1024, 1024);
  k_transpose_bf16<<<dim3(64, 32), 256, 0, stream>>>(W_qk, WqkT, 1024, 2048);
  k_transpose_bf16<<<dim3(32, 32), 256, 0, stream>>>(W_out, WoutT, 1024, 1024);
  k_transpose_bf16<<<dim3(128, 32), 256, 0, stream>>>(W1, W1T, 1024, 4096);
  k_transpose_bf16<<<dim3(32, 128), 256, 0, stream>>>(W2, W2T, 4096, 1024);

  k_layernorm<<<CM, 256, 0, stream>>>(x, ln1_g, ln1_b, hln);

  k_gemm<EP_SILU><<<dim3(8, 64), 256, 0, stream>>>(hln, WactT, 1024, 1024, b_act, nullptr, nullptr, actb);
  k_gemm<EP_PLAIN><<<dim3(8, 64), 256, 0, stream>>>(hln, WinT, 1024, 1024, b_in, nullptr, nullptr, vb);
  k_gemm<EP_ELU1><<<dim3(16, 64), 256, 0, stream>>>(vb, WqkT, 2048, 1024, b_qk, nullptr, nullptr, qkb);

  k_attn_reduce<<<256, 256, 0, stream>>>(qkb, vb, cosT, sinT, kvpart, kmpart);
  k_kv_reduce<<<1024, 256, 0, stream>>>(kvpart, kmpart, kvTb, kmean);
  k_attn_out<<<2048, 256, 0, stream>>>(qkb, kvTb, kmean, cosT, sinT, outlin);
  k_conv_mul<<<32768, 256, 0, stream>>>(outlin, vb, actb, conv_w, conv_b, A4);

  k_gemm<EP_ADDX><<<dim3(8, 64), 256, 0, stream>>>(A4, WoutT, 1024, 1024, b_out, x, x2, nullptr);
  k_layernorm<<<CM, 256, 0, stream>>>(x2, ln2_g, ln2_b, mln);
  k_gemm<EP_GELU><<<dim3(32, 64), 256, 0, stream>>>(mln, W1T, 4096, 1024, b1, nullptr, nullptr, Gb);
  k_gemm<EP_ADDX><<<dim3(8, 64), 256, 0, stream>>>(Gb, W2T, 1024, 4096, b2, x2, out, nullptr);
}